// Round 1
// baseline (1333.906 us; speedup 1.0000x reference)
//
#include <hip/hip_runtime.h>
#include <math.h>

#define DIM   1024
#define INNER 2048
#define BATCH 32

// ---------------------------------------------------------------------------
// K1: q = x@Wq+bq, k = x@Wk+bk, v = x@Wv+bv, fused.
// grid = (BATCH, 16) : blockIdx.y indexes 256-wide column tiles over a virtual
// 4096-column space [q(1024) | k(1024) | v(2048)]. b varies fastest in
// dispatch order so blocks sharing a weight tile are co-resident (L2/L3 reuse).
// ---------------------------------------------------------------------------
__global__ __launch_bounds__(256) void qkv_kernel(
    const float* __restrict__ x,
    const float* __restrict__ Wq, const float* __restrict__ bq,
    const float* __restrict__ Wk, const float* __restrict__ bk,
    const float* __restrict__ Wv, const float* __restrict__ bv,
    float* __restrict__ q, float* __restrict__ k, float* __restrict__ v)
{
    __shared__ float xs[DIM];
    const int b = blockIdx.x;
    const int t = threadIdx.x;

    // stage x row (4 KB) into LDS
    const float4* xsrc = (const float4*)(x + b * DIM);
    float4* xdst = (float4*)xs;
    for (int i = t; i < DIM / 4; i += 256) xdst[i] = xsrc[i];
    __syncthreads();

    const int c = blockIdx.y * 256 + t;   // 0..4095, segment uniform per block
    const float* W; const float* bias; float* outp; int N, n;
    if (c < DIM)          { W = Wq; bias = bq; outp = q; N = DIM;   n = c;           }
    else if (c < 2 * DIM) { W = Wk; bias = bk; outp = k; N = DIM;   n = c - DIM;     }
    else                  { W = Wv; bias = bv; outp = v; N = INNER; n = c - 2 * DIM; }

    float acc = 0.f;
    #pragma unroll 4
    for (int kk = 0; kk < DIM; ++kk)
        acc += xs[kk] * W[(size_t)kk * N + n];
    outp[(size_t)b * N + n] = acc + bias[n];
}

// ---------------------------------------------------------------------------
// K2: one pass over W computing colsum[b,j] = sum_i W[b,i,j] (atomics across
// the 16 row-chunk blocks) and rowsum[b,i] = sum_j W[b,i,j] (complete within
// a block: per-wave shuffle reduce -> LDS, single barrier at end).
// block = 512 threads (float4 => full 2048-wide row), 128 rows per block.
// grid = (BATCH, 16).
// ---------------------------------------------------------------------------
__global__ __launch_bounds__(512) void wsum_kernel(
    const float* __restrict__ W,
    float* __restrict__ colsum, float* __restrict__ rowsum)
{
    const int ROWS = 128;
    __shared__ float rowpart[ROWS][8];   // 8 waves
    const int b    = blockIdx.x;
    const int i0   = blockIdx.y * ROWS;
    const int t    = threadIdx.x;
    const int wave = t >> 6, lane = t & 63;

    const float4* Wp = (const float4*)(W + (size_t)b * INNER * INNER);
    float4 csum = make_float4(0.f, 0.f, 0.f, 0.f);

    #pragma unroll 2
    for (int r = 0; r < ROWS; ++r) {
        const int i = i0 + r;
        float4 w = Wp[(size_t)i * (INNER / 4) + t];
        csum.x += w.x; csum.y += w.y; csum.z += w.z; csum.w += w.w;
        float s = (w.x + w.y) + (w.z + w.w);
        #pragma unroll
        for (int m = 1; m < 64; m <<= 1) s += __shfl_xor(s, m, 64);
        if (lane == 0) rowpart[r][wave] = s;   // each wave owns its column; no barrier
    }
    __syncthreads();
    if (t < ROWS) {
        float s = 0.f;
        #pragma unroll
        for (int wv = 0; wv < 8; ++wv) s += rowpart[t][wv];
        rowsum[b * INNER + i0 + t] = s;
    }
    float* cs = colsum + b * INNER + 4 * t;
    atomicAdd(cs + 0, csum.x);
    atomicAdd(cs + 1, csum.y);
    atomicAdd(cs + 2, csum.z);
    atomicAdd(cs + 3, csum.w);
}

// dpfp "concat(relu(k), relu(-k))" element
__device__ __forceinline__ float xcf(const float* __restrict__ kb, int j) {
    float val = (j < DIM) ? kb[j] : -kb[j - DIM];
    return fmaxf(val, 0.f);
}

// ---------------------------------------------------------------------------
// K3: per-batch vector work. One block per b (256 threads x 8 elems).
// beta = sigmoid(x@Wb + bb); kp = dpfp(k); dv = beta*(v - colsum*kp);
// S = sum_j kp; outv = (rowsum + dv*S) * dpfp(q).
// ---------------------------------------------------------------------------
__global__ __launch_bounds__(256) void vec_kernel(
    const float* __restrict__ x, const float* __restrict__ Wb, const float* __restrict__ bb,
    const float* __restrict__ q, const float* __restrict__ k, const float* __restrict__ v,
    const float* __restrict__ colsum, const float* __restrict__ rowsum,
    float* __restrict__ kp, float* __restrict__ dv, float* __restrict__ outv)
{
    __shared__ float red[4];
    const int b = blockIdx.x, t = threadIdx.x;
    const int wave = t >> 6, lane = t & 63;

    // beta
    const float* xrow = x + b * DIM;
    float bsum = 0.f;
    for (int i = t; i < DIM; i += 256) bsum += xrow[i] * Wb[i];
    #pragma unroll
    for (int m = 1; m < 64; m <<= 1) bsum += __shfl_xor(bsum, m, 64);
    if (lane == 0) red[wave] = bsum;
    __syncthreads();
    const float beta = 1.f / (1.f + expf(-((red[0] + red[1] + red[2] + red[3]) + bb[0])));
    __syncthreads();   // protect red[] before reuse

    const float* kb = k + b * DIM;
    const float* qb = q + b * DIM;
    float skp = 0.f;
    float dvu[8];
    #pragma unroll
    for (int u = 0; u < 8; ++u) {
        const int j = u * 256 + t;
        const float kpj = xcf(kb, j) * xcf(kb, (j + INNER - 1) & (INNER - 1));
        kp[b * INNER + j] = kpj;
        skp += kpj;
        const float dvj = beta * (v[b * INNER + j] - colsum[b * INNER + j] * kpj);
        dvu[u] = dvj;
        dv[b * INNER + j] = dvj;
    }
    #pragma unroll
    for (int m = 1; m < 64; m <<= 1) skp += __shfl_xor(skp, m, 64);
    if (lane == 0) red[wave] = skp;
    __syncthreads();
    const float S = red[0] + red[1] + red[2] + red[3];

    #pragma unroll
    for (int u = 0; u < 8; ++u) {
        const int j = u * 256 + t;
        const float qpj = xcf(qb, j) * xcf(qb, (j + INNER - 1) & (INNER - 1));
        outv[b * INNER + j] = (rowsum[b * INNER + j] + dvu[u] * S) * qpj;
    }
}

// ---------------------------------------------------------------------------
// K4: out = outv @ Wo + bo.  grid = (BATCH, 4), outv row staged in LDS.
// ---------------------------------------------------------------------------
__global__ __launch_bounds__(256) void out_kernel(
    const float* __restrict__ outv, const float* __restrict__ Wo,
    const float* __restrict__ bo, float* __restrict__ out)
{
    __shared__ float os[INNER];
    const int b = blockIdx.x, t = threadIdx.x;
    const float4* src = (const float4*)(outv + b * INNER);
    float4* dst = (float4*)os;
    for (int i = t; i < INNER / 4; i += 256) dst[i] = src[i];
    __syncthreads();

    const int n = blockIdx.y * 256 + t;
    float acc = 0.f;
    #pragma unroll 4
    for (int i = 0; i < INNER; ++i)
        acc += os[i] * Wo[(size_t)i * DIM + n];
    out[b * DIM + n] = acc + bo[n];
}

// ---------------------------------------------------------------------------
// K5: W_new = W + dv[b,i] * kp[b,j], streaming float4 pass. 1 GB HBM traffic.
// ---------------------------------------------------------------------------
__global__ __launch_bounds__(256) void wnew_kernel(
    const float* __restrict__ W, const float* __restrict__ dv,
    const float* __restrict__ kp, float* __restrict__ Wn)
{
    const size_t f = (size_t)blockIdx.x * blockDim.x + threadIdx.x; // float4 idx
    const size_t base = f * 4;
    const int j = (int)(base & (INNER - 1));
    const int i = (int)((base >> 11) & (INNER - 1));
    const int b = (int)(base >> 22);

    const float d = dv[b * INNER + i];
    const float4 k4 = *(const float4*)(kp + b * INNER + j);
    float4 w = ((const float4*)W)[f];
    w.x += d * k4.x; w.y += d * k4.y; w.z += d * k4.z; w.w += d * k4.w;
    ((float4*)Wn)[f] = w;
}

// ---------------------------------------------------------------------------
extern "C" void kernel_launch(void* const* d_in, const int* in_sizes, int n_in,
                              void* d_out, int out_size, void* d_ws, size_t ws_size,
                              hipStream_t stream)
{
    const float* x  = (const float*)d_in[0];
    const float* W  = (const float*)d_in[1];
    const float* Wq = (const float*)d_in[2];
    const float* bq = (const float*)d_in[3];
    const float* Wk = (const float*)d_in[4];
    const float* bk = (const float*)d_in[5];
    const float* Wv = (const float*)d_in[6];
    const float* bv = (const float*)d_in[7];
    const float* Wo = (const float*)d_in[8];
    const float* bo = (const float*)d_in[9];
    const float* Wb = (const float*)d_in[10];
    const float* bb = (const float*)d_in[11];

    float* out = (float*)d_out;                          // [32,1024]
    float* Wn  = (float*)d_out + (size_t)BATCH * DIM;    // [32,2048,2048]

    float* ws = (float*)d_ws;
    float* q      = ws;                         // 32*1024
    float* k      = q + BATCH * DIM;            // 32*1024
    float* v      = k + BATCH * DIM;            // 32*2048
    float* colsum = v + BATCH * INNER;          // 32*2048
    float* rowsum = colsum + BATCH * INNER;     // 32*2048
    float* kp     = rowsum + BATCH * INNER;     // 32*2048
    float* dv     = kp + BATCH * INNER;         // 32*2048
    float* outv   = dv + BATCH * INNER;         // 32*2048

    hipMemsetAsync(colsum, 0, (size_t)BATCH * INNER * sizeof(float), stream);

    qkv_kernel<<<dim3(BATCH, 16), 256, 0, stream>>>(x, Wq, bq, Wk, bk, Wv, bv, q, k, v);
    wsum_kernel<<<dim3(BATCH, 16), 512, 0, stream>>>(W, colsum, rowsum);
    vec_kernel<<<BATCH, 256, 0, stream>>>(x, Wb, bb, q, k, v, colsum, rowsum, kp, dv, outv);
    out_kernel<<<dim3(BATCH, 4), 256, 0, stream>>>(outv, Wo, bo, out);

    const size_t nf4 = (size_t)BATCH * INNER * INNER / 4;   // 33554432
    wnew_kernel<<<(unsigned)(nf4 / 256), 256, 0, stream>>>(W, dv, kp, Wn);
}